// Round 1
// baseline (3037.535 us; speedup 1.0000x reference)
//
#include <hip/hip_runtime.h>
#include <hip/hip_bf16.h>

#define B_ 128
#define T_ 256
#define D_ 256
#define H_ 1024
#define C_ 1000
#define NKC 40   // K-chunks of 32 over K=1280 (first 32 from h, last 8 from x_t)
#define NJB 64   // H/16 column tiles
#define NRT 8    // B/16 row tiles

typedef __attribute__((ext_vector_type(8))) short short8;
typedef __attribute__((ext_vector_type(4))) float floatx4;

static __device__ __forceinline__ unsigned short f2bf(float f) {
  unsigned int u = __builtin_bit_cast(unsigned int, f);
  u += 0x7fffu + ((u >> 16) & 1u);
  return (unsigned short)(u >> 16);
}
static __device__ __forceinline__ float bf2f(unsigned short s) {
  unsigned int u = ((unsigned int)s) << 16;
  return __builtin_bit_cast(float, u);
}
static __device__ __forceinline__ float sigm(float z) {
  return 1.0f / (1.0f + __expf(-z));
}
static __device__ __forceinline__ float tanh_fast(float z) {
  z = fminf(fmaxf(z, -15.f), 15.f);
  float e = __expf(2.f * z);
  return (e - 1.f) / (e + 1.f);
}

// ---------------------------------------------------------------------------
// Pack the 8 weight matrices (4 gates x {W_h [1024x1024], W_x [256x1024]}) into
// bf16, laid out so a wave's B-fragment load is one coalesced dwordx4:
// Wp[jb][kc][g][lane][i]  (jb<64, kc<40, g<4, lane<64, i<8)
// value = W_all[k = kc*32 + (lane>>4)*8 + i][col j = jb*16 + (lane&15)] for gate g,
// where k<1024 -> W_gh etc., k>=1024 -> W_gx etc.
// ---------------------------------------------------------------------------
__global__ __launch_bounds__(256) void pack_w(
    const float* __restrict__ Wgx, const float* __restrict__ Wix,
    const float* __restrict__ Wfx, const float* __restrict__ Wox,
    const float* __restrict__ Wgh, const float* __restrict__ Wih,
    const float* __restrict__ Wfh, const float* __restrict__ Woh,
    unsigned short* __restrict__ Wp) {
  int t = blockIdx.x * blockDim.x + threadIdx.x;  // 655,360 threads
  int L = t & 63;
  int g = (t >> 6) & 3;
  int rest = t >> 8;        // jb*40 + kc
  int kc = rest % 40;
  int jb = rest / 40;
  int n = L & 15, q = L >> 4;
  int j = jb * 16 + n;
  const float* Wh = (g == 0) ? Wgh : (g == 1) ? Wih : (g == 2) ? Wfh : Woh;
  const float* Wx = (g == 0) ? Wgx : (g == 1) ? Wix : (g == 2) ? Wfx : Wox;
  int k0 = kc * 32 + q * 8;
  unsigned int w[4];
#pragma unroll
  for (int i = 0; i < 4; i++) {
    int ka = k0 + 2 * i, kb = k0 + 2 * i + 1;
    float fa = (ka < H_) ? Wh[(size_t)ka * H_ + j] : Wx[(size_t)(ka - H_) * H_ + j];
    float fb = (kb < H_) ? Wh[(size_t)kb * H_ + j] : Wx[(size_t)(kb - H_) * H_ + j];
    w[i] = (unsigned int)f2bf(fa) | ((unsigned int)f2bf(fb) << 16);
  }
  uint4 v = {w[0], w[1], w[2], w[3]};
  *((uint4*)(Wp + (size_t)t * 8)) = v;  // thread-contiguous 16B: perfect coalescing
}

// ---------------------------------------------------------------------------
// Pack x [B][T][D] fp32 -> xb bf16 in per-step A-fragment layout:
// xb[t][rt][kcx][lane][i]: value = x[b = rt*16 + (lane&15)][t][d = kcx*32 + (lane>>4)*8 + i]
// ---------------------------------------------------------------------------
__global__ __launch_bounds__(256) void pack_x(const float* __restrict__ x,
                                              unsigned short* __restrict__ xb) {
  int idx = blockIdx.x * blockDim.x + threadIdx.x;  // 1,048,576 threads
  int d8 = idx & 31;          // which 8-wide d group
  int tt = (idx >> 5) & 255;  // time step
  int b = idx >> 13;          // batch row
  const float* src = x + ((size_t)b * T_ + tt) * D_ + d8 * 8;  // 32B contiguous
  int rt = b >> 4, kcx = d8 >> 2, q = d8 & 3, m = b & 15;
  size_t dst = ((((size_t)tt * 8 + rt) * 8 + kcx) * 64 + (q * 16 + m)) * 8;
  unsigned int w[4];
#pragma unroll
  for (int i = 0; i < 4; i++) {
    float fa = src[2 * i], fb = src[2 * i + 1];
    w[i] = (unsigned int)f2bf(fa) | ((unsigned int)f2bf(fb) << 16);
  }
  uint4 v = {w[0], w[1], w[2], w[3]};
  *((uint4*)(xb + dst)) = v;
}

// ---------------------------------------------------------------------------
// One LSTM time step. Grid 256 x 128 threads (2 waves). Wave (rt, jb) computes
// the 16x16 tile (rows rt*16.., hidden cols jb*16..) for all 4 gates via MFMA
// over K=1280, then does the pointwise cell update in-lane and scatters h_next
// in A-fragment layout for the next step. No LDS, no barriers.
// ---------------------------------------------------------------------------
__global__ __launch_bounds__(128) void lstm_step(
    const unsigned short* __restrict__ hprev, unsigned short* __restrict__ hnext,
    float* __restrict__ c, const unsigned short* __restrict__ Wp,
    const unsigned short* __restrict__ xb, const float* __restrict__ bg,
    const float* __restrict__ bi, const float* __restrict__ bf_,
    const float* __restrict__ bo, int t) {
  int w = threadIdx.x >> 6;
  int lane = threadIdx.x & 63;
  int wave = blockIdx.x * 2 + w;  // 512 waves; jb%8 tracks blockIdx%8 -> XCD-pinned weights
  int jb = wave & 63;
  int rt = wave >> 6;

  const short8* Ah = (const short8*)hprev + (size_t)(rt * 32) * 64 + lane;          // +kc*64
  const short8* Ax = (const short8*)xb + (((size_t)t * 8 + rt) * 8) * 64 + lane;    // +kcx*64
  const short8* Bp = (const short8*)Wp + (size_t)jb * 40 * 4 * 64 + lane;           // +(kc*4+g)*64

  floatx4 acc0 = {0.f, 0.f, 0.f, 0.f};
  floatx4 acc1 = {0.f, 0.f, 0.f, 0.f};
  floatx4 acc2 = {0.f, 0.f, 0.f, 0.f};
  floatx4 acc3 = {0.f, 0.f, 0.f, 0.f};

#pragma unroll 4
  for (int kc = 0; kc < 32; kc++) {  // recurrent part: A from h_prev
    short8 a = Ah[(size_t)kc * 64];
    short8 b0 = Bp[(size_t)(kc * 4 + 0) * 64];
    short8 b1 = Bp[(size_t)(kc * 4 + 1) * 64];
    short8 b2 = Bp[(size_t)(kc * 4 + 2) * 64];
    short8 b3 = Bp[(size_t)(kc * 4 + 3) * 64];
    acc0 = __builtin_amdgcn_mfma_f32_16x16x32_bf16(a, b0, acc0, 0, 0, 0);
    acc1 = __builtin_amdgcn_mfma_f32_16x16x32_bf16(a, b1, acc1, 0, 0, 0);
    acc2 = __builtin_amdgcn_mfma_f32_16x16x32_bf16(a, b2, acc2, 0, 0, 0);
    acc3 = __builtin_amdgcn_mfma_f32_16x16x32_bf16(a, b3, acc3, 0, 0, 0);
  }
#pragma unroll
  for (int kcx = 0; kcx < 8; kcx++) {  // input-projection part: A from x_t
    int kc = 32 + kcx;
    short8 a = Ax[(size_t)kcx * 64];
    short8 b0 = Bp[(size_t)(kc * 4 + 0) * 64];
    short8 b1 = Bp[(size_t)(kc * 4 + 1) * 64];
    short8 b2 = Bp[(size_t)(kc * 4 + 2) * 64];
    short8 b3 = Bp[(size_t)(kc * 4 + 3) * 64];
    acc0 = __builtin_amdgcn_mfma_f32_16x16x32_bf16(a, b0, acc0, 0, 0, 0);
    acc1 = __builtin_amdgcn_mfma_f32_16x16x32_bf16(a, b1, acc1, 0, 0, 0);
    acc2 = __builtin_amdgcn_mfma_f32_16x16x32_bf16(a, b2, acc2, 0, 0, 0);
    acc3 = __builtin_amdgcn_mfma_f32_16x16x32_bf16(a, b3, acc3, 0, 0, 0);
  }

  // Epilogue: C/D layout col = lane&15, row = (lane>>4)*4 + reg
  int cl = lane & 15, q = lane >> 4;
  int j = jb * 16 + cl;
  float vbg = bg[j], vbi = bi[j], vbf = bf_[j], vbo = bo[j];
#pragma unroll
  for (int p = 0; p < 4; p++) {
    int r = rt * 16 + q * 4 + p;
    float gg = tanh_fast(acc0[p] + vbg);
    float ii = sigm(acc1[p] + vbi);
    float ff = sigm(acc2[p] + vbf);
    float oo = sigm(acc3[p] + vbo);
    float cold = c[(size_t)r * H_ + j];
    float cn = gg * ii + cold * ff;
    c[(size_t)r * H_ + j] = cn;
    float hn = tanh_fast(cn) * oo;
    // scatter into next step's A-fragment layout (same rt since r in [rt*16, rt*16+16))
    size_t dst = ((size_t)(rt * 32 + (j >> 5)) * 64 + (((j >> 3) & 3) * 16 + (q * 4 + p))) * 8 + (j & 7);
    hnext[dst] = f2bf(hn);
  }
}

// ---------------------------------------------------------------------------
// Final projection p = h_T @ W_ph + b_p and row-wise log_softmax.
// One block per batch row; h row staged to LDS from A-fragment layout.
// ---------------------------------------------------------------------------
__global__ __launch_bounds__(256) void final_proj(const unsigned short* __restrict__ hB,
                                                  const float* __restrict__ Wph,
                                                  const float* __restrict__ bp,
                                                  float* __restrict__ out) {
  __shared__ float hrow[H_];
  __shared__ float red[256];
  int row = blockIdx.x, tid = threadIdx.x;
  int rt = row >> 4, m = row & 15;
#pragma unroll
  for (int i = 0; i < 4; i++) {
    int k = tid * 4 + i;
    size_t idx = ((size_t)(rt * 32 + (k >> 5)) * 64 + (((k >> 3) & 3) * 16 + m)) * 8 + (k & 7);
    hrow[k] = bf2f(hB[idx]);
  }
  __syncthreads();

  int c3 = (tid + 768 < C_) ? (tid + 768) : (C_ - 1);  // clamp (only tid<232 valid)
  float a0 = 0.f, a1 = 0.f, a2 = 0.f, a3 = 0.f;
#pragma unroll 4
  for (int k = 0; k < H_; k++) {
    float hv = hrow[k];
    const float* wr = Wph + (size_t)k * C_;
    a0 += hv * wr[tid];
    a1 += hv * wr[tid + 256];
    a2 += hv * wr[tid + 512];
    a3 += hv * wr[c3];
  }
  a0 += bp[tid];
  a1 += bp[tid + 256];
  a2 += bp[tid + 512];
  a3 += bp[c3];

  bool v3 = (tid + 768 < C_);
  float mx = fmaxf(fmaxf(a0, a1), a2);
  if (v3) mx = fmaxf(mx, a3);
  red[tid] = mx;
  __syncthreads();
  for (int s = 128; s > 0; s >>= 1) {
    if (tid < s) red[tid] = fmaxf(red[tid], red[tid + s]);
    __syncthreads();
  }
  float M = red[0];
  __syncthreads();
  float se = __expf(a0 - M) + __expf(a1 - M) + __expf(a2 - M);
  if (v3) se += __expf(a3 - M);
  red[tid] = se;
  __syncthreads();
  for (int s = 128; s > 0; s >>= 1) {
    if (tid < s) red[tid] += red[tid + s];
    __syncthreads();
  }
  float lse = M + logf(red[0]);
  out[(size_t)row * C_ + tid] = a0 - lse;
  out[(size_t)row * C_ + tid + 256] = a1 - lse;
  out[(size_t)row * C_ + tid + 512] = a2 - lse;
  if (v3) out[(size_t)row * C_ + tid + 768] = a3 - lse;
}

extern "C" void kernel_launch(void* const* d_in, const int* in_sizes, int n_in,
                              void* d_out, int out_size, void* d_ws, size_t ws_size,
                              hipStream_t stream) {
  const float* x   = (const float*)d_in[0];
  const float* Wgx = (const float*)d_in[1];
  const float* Wix = (const float*)d_in[2];
  const float* Wfx = (const float*)d_in[3];
  const float* Wox = (const float*)d_in[4];
  const float* Wgh = (const float*)d_in[5];
  const float* Wih = (const float*)d_in[6];
  const float* Wfh = (const float*)d_in[7];
  const float* Woh = (const float*)d_in[8];
  const float* Wph = (const float*)d_in[9];
  const float* bg  = (const float*)d_in[10];
  const float* bi  = (const float*)d_in[11];
  const float* bf  = (const float*)d_in[12];
  const float* bo  = (const float*)d_in[13];
  const float* bp  = (const float*)d_in[14];

  char* ws = (char*)d_ws;
  unsigned short* Wp = (unsigned short*)ws;                 // 10,485,760 B
  size_t off = 10485760;
  unsigned short* xb = (unsigned short*)(ws + off); off += 16777216;  // 16 MB
  unsigned short* h0 = (unsigned short*)(ws + off); off += 262144;
  unsigned short* h1 = (unsigned short*)(ws + off); off += 262144;
  float* c = (float*)(ws + off); off += 524288;             // total ~28.3 MB

  hipMemsetAsync(h0, 0, 262144, stream);
  hipMemsetAsync(c, 0, 524288, stream);

  pack_w<<<2560, 256, 0, stream>>>(Wgx, Wix, Wfx, Wox, Wgh, Wih, Wfh, Woh, Wp);
  pack_x<<<4096, 256, 0, stream>>>(x, xb);

  unsigned short* bufs[2] = {h0, h1};
  for (int t = 0; t < T_; t++) {
    lstm_step<<<256, 128, 0, stream>>>(bufs[t & 1], bufs[(t + 1) & 1], c, Wp, xb,
                                       bg, bi, bf, bo, t);
  }
  // after 256 steps the final h is in bufs[0]
  final_proj<<<128, 256, 0, stream>>>(bufs[0], Wph, bp, (float*)d_out);
}